// Round 1
// baseline (1457.437 us; speedup 1.0000x reference)
//
#include <hip/hip_runtime.h>
#include <math.h>

// ---------------------------------------------------------------------------
// OP3 Physics Network forward, fp32. Sizes: B=32,L=32,N=8,D=256,A=16,AENC=32,EFF=32
// Tokens: BLN = 8192 node tokens, pairs = 8192*7.
// Key restructure: pairs@pw_w1 = U[i]+V[j] with U=senc@W1top+b1, V=senc@W1bot.
// This round: software-pipelined (double-buffered) GEMM + jj-batched pair phase.
// ---------------------------------------------------------------------------

#define BLN 8192
#define BL  1024

__device__ __forceinline__ float eluf(float x)  { return x > 0.0f ? x : expm1f(x); }
__device__ __forceinline__ float sigmf_(float x){ return 1.0f / (1.0f + expf(-x)); }

// ---------------------------------------------------------------------------
// Generic tiled GEMM: C[M,N] = act(A[M,K] @ W[K,N] + bias) [* rowscale[row]]
// 64x64 tile, BK=32, 256 threads, 4x4 per thread.
// Double-buffered LDS; global loads for tile t+1 issued right after the
// barrier (latency hidden under tile-t compute); LDS writes deferred to
// after compute (async-stage split). One barrier per K-step.
// PAIRGATHER: A_virtual[r,k] = elu(U[r,k] + V[vrow(r),k]), lda = 512.
//   jj >= 0: fixed pair index (serial fallback path)
//   jj <  0: batched, jj derived from virtual row (gr >> 13), M = 7*8192.
// ---------------------------------------------------------------------------
template<int ACT, bool ROWSCALE, bool PAIRGATHER>
__global__ __launch_bounds__(256) void gemm_k(
    const float* __restrict__ A, int lda,
    const float* __restrict__ W, int ldw,
    const float* __restrict__ bias,
    float* __restrict__ C, int ldc,
    int K,
    const float* __restrict__ rowscale,
    const float* __restrict__ Vm, int jj)
{
  __shared__ float As[2][32][68];   // k-major, padded
  __shared__ float Ws[2][32][64];   // k-major (natural)
  const int m0 = blockIdx.x * 64;
  const int n0 = blockIdx.y * 64;
  const int tid = threadIdx.x;

  // staging roles
  const int arow = tid >> 2;            // 0..63
  const int akg  = (tid & 3) << 3;      // 0,8,16,24
  const int wrow = tid >> 3;            // 0..31
  const int wcg  = (tid & 7) << 3;      // 0..56

  // compute roles
  const int tr = (tid >> 4) << 2;       // 0..60
  const int tc = (tid & 15) << 2;       // 0..60

  const int gr = m0 + arow;
  const float* aptr;
  const float* vptr = nullptr;
  if (PAIRGATHER) {
    const int jjv = (jj >= 0) ? jj : (gr >> 13);
    const int r = gr & (BLN - 1);
    const int i = r & 7;
    const int j = jjv + ((jjv >= i) ? 1 : 0);
    const int vr = (r & ~7) | j;
    aptr = A  + (size_t)r * lda + akg;
    vptr = Vm + (size_t)vr * lda + akg;
  } else {
    aptr = A + (size_t)gr * lda + akg;
  }
  const float* wptr = W + (size_t)wrow * ldw + n0 + wcg;

  float acc[4][4] = {};

  // staging registers (raw; activation applied at LDS-write time so the
  // vmcnt wait lands after the compute phase, not before it)
  float4 ra0, ra1, rv0, rv1, rw0, rw1;

  auto LOAD = [&](int k0) {
    ra0 = *(const float4*)(aptr + k0);
    ra1 = *(const float4*)(aptr + k0 + 4);
    if (PAIRGATHER) {
      rv0 = *(const float4*)(vptr + k0);
      rv1 = *(const float4*)(vptr + k0 + 4);
    }
    rw0 = *(const float4*)(wptr + (size_t)k0 * ldw);
    rw1 = *(const float4*)(wptr + (size_t)k0 * ldw + 4);
  };
  auto STORE = [&](int buf) {
    float av[8];
    if (PAIRGATHER) {
      av[0]=eluf(ra0.x+rv0.x); av[1]=eluf(ra0.y+rv0.y); av[2]=eluf(ra0.z+rv0.z); av[3]=eluf(ra0.w+rv0.w);
      av[4]=eluf(ra1.x+rv1.x); av[5]=eluf(ra1.y+rv1.y); av[6]=eluf(ra1.z+rv1.z); av[7]=eluf(ra1.w+rv1.w);
    } else {
      av[0]=ra0.x; av[1]=ra0.y; av[2]=ra0.z; av[3]=ra0.w;
      av[4]=ra1.x; av[5]=ra1.y; av[6]=ra1.z; av[7]=ra1.w;
    }
#pragma unroll
    for (int i2 = 0; i2 < 8; ++i2) As[buf][akg + i2][arow] = av[i2];
    *(float4*)&Ws[buf][wrow][wcg]     = rw0;
    *(float4*)&Ws[buf][wrow][wcg + 4] = rw1;
  };

  LOAD(0);
  STORE(0);
  const int nt = K >> 5;
  for (int t = 0; t < nt; ++t) {
    __syncthreads();                 // tile t fully staged in buf (t&1)
    const bool more = (t + 1 < nt);
    if (more) LOAD((t + 1) << 5);    // issue early; consumed after compute
    const int b = t & 1;
#pragma unroll
    for (int k = 0; k < 32; ++k) {
      float4 a = *(const float4*)&As[b][k][tr];
      float4 w = *(const float4*)&Ws[b][k][tc];
      acc[0][0] += a.x*w.x; acc[0][1] += a.x*w.y; acc[0][2] += a.x*w.z; acc[0][3] += a.x*w.w;
      acc[1][0] += a.y*w.x; acc[1][1] += a.y*w.y; acc[1][2] += a.y*w.z; acc[1][3] += a.y*w.w;
      acc[2][0] += a.z*w.x; acc[2][1] += a.z*w.y; acc[2][2] += a.z*w.z; acc[2][3] += a.z*w.w;
      acc[3][0] += a.w*w.x; acc[3][1] += a.w*w.y; acc[3][2] += a.w*w.z; acc[3][3] += a.w*w.w;
    }
    if (more) STORE((t + 1) & 1);    // write to the *other* buffer: no race
  }

  float bv[4] = {0.f, 0.f, 0.f, 0.f};
  if (bias) {
    float4 bq = *(const float4*)(bias + n0 + tc);
    bv[0]=bq.x; bv[1]=bq.y; bv[2]=bq.z; bv[3]=bq.w;
  }
#pragma unroll
  for (int i = 0; i < 4; ++i) {
    const int r = m0 + tr + i;
    float v0 = acc[i][0] + bv[0];
    float v1 = acc[i][1] + bv[1];
    float v2 = acc[i][2] + bv[2];
    float v3 = acc[i][3] + bv[3];
    if (ACT == 1) { v0=eluf(v0); v1=eluf(v1); v2=eluf(v2); v3=eluf(v3); }
    else if (ACT == 2) { v0=sigmf_(v0); v1=sigmf_(v1); v2=sigmf_(v2); v3=sigmf_(v3); }
    if (ROWSCALE) { float s = rowscale[r]; v0*=s; v1*=s; v2*=s; v3*=s; }
    float4 o; o.x=v0; o.y=v1; o.z=v2; o.w=v3;
    *(float4*)&C[(size_t)r * ldc + n0 + tc] = o;
  }
}

// ---------------------------------------------------------------------------
// Action-encoder MLP: one block per (b,l) token. one_hot @ w1 == w1[a].
// ---------------------------------------------------------------------------
__global__ __launch_bounds__(256) void ae_kernel(
    const int* __restrict__ action,
    const float* __restrict__ w1, const float* __restrict__ b1,
    const float* __restrict__ w2, const float* __restrict__ b2,
    float* __restrict__ aenc)
{
  __shared__ float hs[256];
  const int bl = blockIdx.x;
  const int t = threadIdx.x;
  const int a = action[bl];
  hs[t] = eluf(w1[a * 256 + t] + b1[t]);
  __syncthreads();
  if (t < 32) {
    float acc = 0.f;
    for (int k = 0; k < 256; ++k) acc += hs[k] * w2[k * 32 + t];
    aenc[bl * 32 + t] = eluf(acc + b2[t]);
  }
}

// fill sa2[:, 256:288] with broadcast aenc
__global__ __launch_bounds__(256) void sa_fill_kernel(const float* __restrict__ aenc,
                                                      float* __restrict__ sa2)
{
  const int idx = blockIdx.x * 256 + threadIdx.x;  // 8192*32
  const int r = idx >> 5, c = idx & 31;
  sa2[(size_t)r * 288 + 256 + c] = aenc[(r >> 3) * 32 + c];
}

// zero sa2[:, 256:288] (total_effect accumulator; serial fallback path only)
__global__ __launch_bounds__(256) void zero_teff_kernel(float* __restrict__ sa2)
{
  const int idx = blockIdx.x * 256 + threadIdx.x;
  const int r = idx >> 5, c = idx & 31;
  sa2[(size_t)r * 288 + 256 + c] = 0.f;
}

// s_att[row] = sigmoid(dot(h_ea[row,256:512], aat_w2) + aat_b2). 4 rows/block.
__global__ __launch_bounds__(256) void satt_kernel(
    const float* __restrict__ hea, const float* __restrict__ w,
    const float* __restrict__ b, float* __restrict__ satt)
{
  const int wv = threadIdx.x >> 6;
  const int lane = threadIdx.x & 63;
  const int row = blockIdx.x * 4 + wv;
  const float* h = hea + (size_t)row * 512 + 256;
  float acc = 0.f;
#pragma unroll
  for (int m = 0; m < 4; ++m) acc += h[lane + 64 * m] * w[lane + 64 * m];
#pragma unroll
  for (int off = 32; off; off >>= 1) acc += __shfl_xor(acc, off, 64);
  if (lane == 0) satt[row] = sigmf_(acc + b[0]);
}

// ie/ia layer-2 + p_eff*p_att + accumulate into total_effect (sa2 cols 256:288).
// Serial fallback: one jj slice, RMW accumulate. 8 rows per block.
__global__ __launch_bounds__(256) void pair_l2_kernel(
    const float* __restrict__ h,
    const float* __restrict__ ie_w2, const float* __restrict__ ie_b2,
    const float* __restrict__ ia_w2, const float* __restrict__ ia_b2,
    float* __restrict__ sa2)
{
  __shared__ float hs[8][512];
  __shared__ float pas[8];
  const int r0 = blockIdx.x * 8;
  const int tid = threadIdx.x;
#pragma unroll
  for (int it = 0; it < 4; ++it) {
    const int f4 = it * 256 + tid;       // 1024 float4s
    const int rr = f4 >> 7;
    const int cc = (f4 & 127) << 2;
    *(float4*)&hs[rr][cc] = *(const float4*)&h[(size_t)(r0 + rr) * 512 + cc];
  }
  __syncthreads();
  const int row = tid >> 5;
  const int col = tid & 31;
  float pa = 0.f;
#pragma unroll
  for (int m = 0; m < 8; ++m) pa += hs[row][256 + col + 32 * m] * ia_w2[col + 32 * m];
#pragma unroll
  for (int off = 16; off; off >>= 1) pa += __shfl_xor(pa, off, 64);
  if (col == 0) pas[row] = sigmf_(pa + ia_b2[0]);
  float acc = 0.f;
  for (int k = 0; k < 256; ++k) acc += hs[row][k] * ie_w2[k * 32 + col];
  __syncthreads();
  const float val = eluf(acc + ie_b2[col]) * pas[row];
  sa2[(size_t)(r0 + row) * 288 + 256 + col] += val;
}

// Batched variant: h is [7*8192, 512]; loop jj internally, accumulate in regs,
// single write (no zero-init, no global RMW).
__global__ __launch_bounds__(256) void pair_l2_all_kernel(
    const float* __restrict__ h,
    const float* __restrict__ ie_w2, const float* __restrict__ ie_b2,
    const float* __restrict__ ia_w2, const float* __restrict__ ia_b2,
    float* __restrict__ sa2)
{
  __shared__ float hs[8][512];
  __shared__ float pas[8];
  const int r0 = blockIdx.x * 8;
  const int tid = threadIdx.x;
  const int row = tid >> 5;
  const int col = tid & 31;
  float teff = 0.f;
  for (int jj = 0; jj < 7; ++jj) {
    __syncthreads();   // previous iteration's hs fully consumed
    const float* hb = h + ((size_t)jj * BLN + r0) * 512;
#pragma unroll
    for (int it = 0; it < 4; ++it) {
      const int f4 = it * 256 + tid;
      const int rr = f4 >> 7;
      const int cc = (f4 & 127) << 2;
      *(float4*)&hs[rr][cc] = *(const float4*)&hb[(size_t)rr * 512 + cc];
    }
    __syncthreads();
    float pa = 0.f;
#pragma unroll
    for (int m = 0; m < 8; ++m) pa += hs[row][256 + col + 32 * m] * ia_w2[col + 32 * m];
#pragma unroll
    for (int off = 16; off; off >>= 1) pa += __shfl_xor(pa, off, 64);
    if (col == 0) pas[row] = sigmf_(pa + ia_b2[0]);
    float acc = 0.f;
    for (int k = 0; k < 256; ++k) acc += hs[row][k] * ie_w2[k * 32 + col];
    __syncthreads();   // pas[row] visible (and hs consumed before next jj)
    teff += eluf(acc + ie_b2[col]) * pas[row];
  }
  sa2[(size_t)(r0 + row) * 288 + 256 + col] = teff;
}

// weight concat: dst[k, 0:N]=a, dst[k, N:2N]=b  (dst is [K, 2N])
__global__ __launch_bounds__(256) void concat_w_kernel(
    const float* __restrict__ a, const float* __restrict__ b,
    float* __restrict__ dst, int N)
{
  const int idx = blockIdx.x * 256 + threadIdx.x;
  const int k = idx / (2 * N);
  const int n = idx % (2 * N);
  dst[idx] = (n < N) ? a[k * N + n] : b[k * N + (n - N)];
}

__global__ __launch_bounds__(512) void concat_b_kernel(
    const float* __restrict__ a, const float* __restrict__ b,
    float* __restrict__ dst, int N)
{
  const int t = threadIdx.x;
  dst[t] = (t < N) ? a[t] : b[t - N];
}

// ---------------------------------------------------------------------------
extern "C" void kernel_launch(void* const* d_in, const int* in_sizes, int n_in,
                              void* d_out, int out_size, void* d_ws, size_t ws_size,
                              hipStream_t stream) {
  const float* samples = (const float*)d_in[0];
  const int*   action  = (const int*)d_in[1];
  // d_in[2] mask: unused by the forward pass
  const float* in_w1  = (const float*)d_in[3];
  const float* in_b1  = (const float*)d_in[4];
  const float* in_w2  = (const float*)d_in[5];
  const float* in_b2  = (const float*)d_in[6];
  const float* ae_w1  = (const float*)d_in[7];
  const float* ae_b1  = (const float*)d_in[8];
  const float* ae_w2  = (const float*)d_in[9];
  const float* ae_b2  = (const float*)d_in[10];
  const float* eff_w1 = (const float*)d_in[11];
  const float* eff_b1 = (const float*)d_in[12];
  const float* eff_w2 = (const float*)d_in[13];
  const float* eff_b2 = (const float*)d_in[14];
  const float* aat_w1 = (const float*)d_in[15];
  const float* aat_b1 = (const float*)d_in[16];
  const float* aat_w2 = (const float*)d_in[17];
  const float* aat_b2 = (const float*)d_in[18];
  const float* pw_w1  = (const float*)d_in[19];
  const float* pw_b1  = (const float*)d_in[20];
  const float* pw_w2  = (const float*)d_in[21];
  const float* pw_b2  = (const float*)d_in[22];
  const float* ie_w1  = (const float*)d_in[23];
  const float* ie_b1  = (const float*)d_in[24];
  const float* ie_w2  = (const float*)d_in[25];
  const float* ie_b2  = (const float*)d_in[26];
  const float* ia_w1  = (const float*)d_in[27];
  const float* ia_b1  = (const float*)d_in[28];
  const float* ia_w2  = (const float*)d_in[29];
  const float* ia_b2  = (const float*)d_in[30];
  const float* fm_w1  = (const float*)d_in[31];
  const float* fm_b1  = (const float*)d_in[32];
  const float* fm_w2  = (const float*)d_in[33];
  const float* fm_b2  = (const float*)d_in[34];
  const float* out_w1 = (const float*)d_in[35];
  const float* out_b1 = (const float*)d_in[36];
  const float* out_w2 = (const float*)d_in[37];
  const float* out_b2 = (const float*)d_in[38];
  float* out = (float*)d_out;

  // workspace arena (floats)
  float* ws = (float*)d_ws;
  float* sa2     = ws;                         // [8192, 288] sa / state_enc+teff / merged_in
  float* h1      = sa2     + (size_t)BLN*288;  // [8192, 256]
  float* hea     = h1      + (size_t)BLN*256;  // [8192, 512]
  float* U       = hea     + (size_t)BLN*512;  // [8192, 512]
  float* V       = U       + (size_t)BLN*512;  // [8192, 512]
  float* pint    = V       + (size_t)BLN*512;  // [8192, 256]
  float* aenc    = pint    + (size_t)BLN*256;  // [1024, 32]
  float* satt    = aenc    + (size_t)BL*32;    // [8192]
  float* wcat_ea = satt    + BLN;              // [288, 512]
  float* bcat_ea = wcat_ea + 288*512;          // [512]
  float* wcat_ii = bcat_ea + 512;              // [256, 512]
  float* bcat_ii = wcat_ii + 256*512;          // [512]
  float* arena_end = bcat_ii + 512;            // 19,457,024 floats
  // batched pair-phase buffers (only if workspace allows)
  float* pint_all = arena_end;                      // [7*8192, 256] = 14,680,064
  float* hea_all  = pint_all + (size_t)7*BLN*256;   // [7*8192, 512] = 29,360,128
  const size_t need_batched = ((size_t)63497216) * sizeof(float);
  const bool batched = (ws_size >= need_batched);

  const dim3 blk(256);

  // weight prep
  concat_w_kernel<<<dim3(288*512/256), blk, 0, stream>>>(eff_w1, aat_w1, wcat_ea, 256);
  concat_b_kernel<<<dim3(1), dim3(512), 0, stream>>>(eff_b1, aat_b1, bcat_ea, 256);
  concat_w_kernel<<<dim3(256*512/256), blk, 0, stream>>>(ie_w1, ia_w1, wcat_ii, 256);
  concat_b_kernel<<<dim3(1), dim3(512), 0, stream>>>(ie_b1, ia_b1, bcat_ii, 256);

  // action encoder
  ae_kernel<<<dim3(BL), blk, 0, stream>>>(action, ae_w1, ae_b1, ae_w2, ae_b2, aenc);

  // in_ MLP: samples -> h1 -> sa2[:, :256]
  gemm_k<1,false,false><<<dim3(128,4), blk, 0, stream>>>(samples, 256, in_w1, 256, in_b1, h1, 256, 256, nullptr, nullptr, 0);
  gemm_k<1,false,false><<<dim3(128,4), blk, 0, stream>>>(h1, 256, in_w2, 256, in_b2, sa2, 288, 256, nullptr, nullptr, 0);
  sa_fill_kernel<<<dim3(BLN*32/256), blk, 0, stream>>>(aenc, sa2);

  // eff/aat layer1 (fused) -> hea[8192,512]
  gemm_k<1,false,false><<<dim3(128,8), blk, 0, stream>>>(sa2, 288, wcat_ea, 512, bcat_ea, hea, 512, 288, nullptr, nullptr, 0);
  // s_att
  satt_kernel<<<dim3(BLN/4), blk, 0, stream>>>(hea, aat_w2, aat_b2, satt);
  // eff layer2 with rowscale -> state_enc into sa2[:, :256]
  gemm_k<1,true,false><<<dim3(128,4), blk, 0, stream>>>(hea, 512, eff_w2, 256, eff_b2, sa2, 288, 256, satt, nullptr, 0);

  // U = senc @ pw_w1[:256,:] + pw_b1 ; V = senc @ pw_w1[256:,:]
  gemm_k<0,false,false><<<dim3(128,8), blk, 0, stream>>>(sa2, 288, pw_w1, 512, pw_b1, U, 512, 256, nullptr, nullptr, 0);
  gemm_k<0,false,false><<<dim3(128,8), blk, 0, stream>>>(sa2, 288, pw_w1 + 256*512, 512, nullptr, V, 512, 256, nullptr, nullptr, 0);

  if (batched) {
    // all 7 jj slices in one dispatch each: grid 896x4 / 896x8 (full CU fill)
    gemm_k<1,false,true><<<dim3(128*7,4), blk, 0, stream>>>(U, 512, pw_w2, 256, pw_b2, pint_all, 256, 512, nullptr, V, -1);
    gemm_k<1,false,false><<<dim3(128*7,8), blk, 0, stream>>>(pint_all, 256, wcat_ii, 512, bcat_ii, hea_all, 512, 256, nullptr, nullptr, 0);
    pair_l2_all_kernel<<<dim3(BLN/8), blk, 0, stream>>>(hea_all, ie_w2, ie_b2, ia_w2, ia_b2, sa2);
  } else {
    // serial fallback (original path)
    zero_teff_kernel<<<dim3(BLN*32/256), blk, 0, stream>>>(sa2);
    for (int jj = 0; jj < 7; ++jj) {
      gemm_k<1,false,true><<<dim3(128,4), blk, 0, stream>>>(U, 512, pw_w2, 256, pw_b2, pint, 256, 512, nullptr, V, jj);
      gemm_k<1,false,false><<<dim3(128,8), blk, 0, stream>>>(pint, 256, wcat_ii, 512, bcat_ii, hea, 512, 256, nullptr, nullptr, 0);
      pair_l2_kernel<<<dim3(BLN/8), blk, 0, stream>>>(hea, ie_w2, ie_b2, ia_w2, ia_b2, sa2);
    }
  }

  // fm MLP: sa2[8192,288] -> h1 -> merged (pint)
  gemm_k<1,false,false><<<dim3(128,4), blk, 0, stream>>>(sa2, 288, fm_w1, 256, fm_b1, h1, 256, 288, nullptr, nullptr, 0);
  gemm_k<1,false,false><<<dim3(128,4), blk, 0, stream>>>(h1, 256, fm_w2, 256, fm_b2, pint, 256, 256, nullptr, nullptr, 0);

  // out MLP: merged -> h1 -> d_out
  gemm_k<1,false,false><<<dim3(128,4), blk, 0, stream>>>(pint, 256, out_w1, 256, out_b1, h1, 256, 256, nullptr, nullptr, 0);
  gemm_k<0,false,false><<<dim3(128,4), blk, 0, stream>>>(h1, 256, out_w2, 256, out_b2, out, 256, 256, nullptr, nullptr, 0);
}

// Round 2
// 958.348 us; speedup vs baseline: 1.5208x; 1.5208x over previous
//
#include <hip/hip_runtime.h>
#include <math.h>

// ---------------------------------------------------------------------------
// OP3 Physics Network forward, fp32. Sizes: B=32,L=32,N=8,D=256,A=16,AENC=32,EFF=32
// Tokens: BLN = 8192 node tokens, pairs = 8192*7.
// Key restructure: pairs@pw_w1 = U[i]+V[j] with U=senc@W1top+b1, V=senc@W1bot.
// Round 2: round-0 single-buffered GEMM (68 VGPR — occupancy-friendly) +
// jj-batched pair phase (3584/7168-block dispatches -> ~7 blocks/CU TLP).
// Round-1 post-mortem: double-buffered GEMM tripled VGPR (68->164), occupancy
// 18->12%, per-block eff -40%. TLP via batching > ILP via dbuf here.
// ---------------------------------------------------------------------------

#define BLN 8192
#define BL  1024

__device__ __forceinline__ float eluf(float x)  { return x > 0.0f ? x : expm1f(x); }
__device__ __forceinline__ float sigmf_(float x){ return 1.0f / (1.0f + expf(-x)); }

// ---------------------------------------------------------------------------
// Generic tiled GEMM: C[M,N] = act(A[M,K] @ W[K,N] + bias) [* rowscale[row]]
// 64x64 tile, BK=32, 256 threads, 4x4 per thread. Single-buffered LDS.
// PAIRGATHER: A_virtual[r,k] = elu(U[r,k] + V[vrow(r),k]), lda = 512.
//   jj >= 0: fixed pair index (serial fallback path)
//   jj <  0: batched, jj derived from virtual row (gr >> 13), M = 7*8192.
// ---------------------------------------------------------------------------
template<int ACT, bool ROWSCALE, bool PAIRGATHER>
__global__ __launch_bounds__(256) void gemm_k(
    const float* __restrict__ A, int lda,
    const float* __restrict__ W, int ldw,
    const float* __restrict__ bias,
    float* __restrict__ C, int ldc,
    int K,
    const float* __restrict__ rowscale,
    const float* __restrict__ Vm, int jj)
{
  __shared__ float As[32][68];   // k-major, padded
  __shared__ float Ws[32][64];   // k-major (natural)
  const int m0 = blockIdx.x * 64;
  const int n0 = blockIdx.y * 64;
  const int tid = threadIdx.x;

  // staging roles
  const int arow = tid >> 2;            // 0..63
  const int akg  = (tid & 3) << 3;      // 0,8,16,24
  const int wrow = tid >> 3;            // 0..31
  const int wcg  = (tid & 7) << 3;      // 0..56

  // compute roles
  const int tr = (tid >> 4) << 2;       // 0..60
  const int tc = (tid & 15) << 2;       // 0..60

  const int gr = m0 + arow;
  const float* aptr;
  const float* vptr = nullptr;
  if (PAIRGATHER) {
    const int jjv = (jj >= 0) ? jj : (gr >> 13);
    const int r = gr & (BLN - 1);
    const int i = r & 7;
    const int j = jjv + ((jjv >= i) ? 1 : 0);
    const int vr = (r & ~7) | j;
    aptr = A  + (size_t)r * lda + akg;
    vptr = Vm + (size_t)vr * lda + akg;
  } else {
    aptr = A + (size_t)gr * lda + akg;
  }
  const float* wptr = W + (size_t)wrow * ldw + n0 + wcg;

  float acc[4][4] = {};

  for (int k0 = 0; k0 < K; k0 += 32) {
    float av[8];
    if (PAIRGATHER) {
      float4 u0 = *(const float4*)(aptr + k0);
      float4 u1 = *(const float4*)(aptr + k0 + 4);
      float4 v0 = *(const float4*)(vptr + k0);
      float4 v1 = *(const float4*)(vptr + k0 + 4);
      av[0]=eluf(u0.x+v0.x); av[1]=eluf(u0.y+v0.y); av[2]=eluf(u0.z+v0.z); av[3]=eluf(u0.w+v0.w);
      av[4]=eluf(u1.x+v1.x); av[5]=eluf(u1.y+v1.y); av[6]=eluf(u1.z+v1.z); av[7]=eluf(u1.w+v1.w);
    } else {
      float4 a0 = *(const float4*)(aptr + k0);
      float4 a1 = *(const float4*)(aptr + k0 + 4);
      av[0]=a0.x; av[1]=a0.y; av[2]=a0.z; av[3]=a0.w;
      av[4]=a1.x; av[5]=a1.y; av[6]=a1.z; av[7]=a1.w;
    }
    float4 w0 = *(const float4*)(wptr + (size_t)k0 * ldw);
    float4 w1 = *(const float4*)(wptr + (size_t)k0 * ldw + 4);

    __syncthreads();   // previous tile fully consumed before overwrite
#pragma unroll
    for (int i = 0; i < 8; ++i) As[akg + i][arow] = av[i];
    *(float4*)&Ws[wrow][wcg]     = w0;
    *(float4*)&Ws[wrow][wcg + 4] = w1;
    __syncthreads();

#pragma unroll
    for (int k = 0; k < 32; ++k) {
      float4 a = *(const float4*)&As[k][tr];
      float4 w = *(const float4*)&Ws[k][tc];
      acc[0][0] += a.x*w.x; acc[0][1] += a.x*w.y; acc[0][2] += a.x*w.z; acc[0][3] += a.x*w.w;
      acc[1][0] += a.y*w.x; acc[1][1] += a.y*w.y; acc[1][2] += a.y*w.z; acc[1][3] += a.y*w.w;
      acc[2][0] += a.z*w.x; acc[2][1] += a.z*w.y; acc[2][2] += a.z*w.z; acc[2][3] += a.z*w.w;
      acc[3][0] += a.w*w.x; acc[3][1] += a.w*w.y; acc[3][2] += a.w*w.z; acc[3][3] += a.w*w.w;
    }
  }

  float bv[4] = {0.f, 0.f, 0.f, 0.f};
  if (bias) {
    float4 b = *(const float4*)(bias + n0 + tc);
    bv[0]=b.x; bv[1]=b.y; bv[2]=b.z; bv[3]=b.w;
  }
#pragma unroll
  for (int i = 0; i < 4; ++i) {
    const int r = m0 + tr + i;
    float v0 = acc[i][0] + bv[0];
    float v1 = acc[i][1] + bv[1];
    float v2 = acc[i][2] + bv[2];
    float v3 = acc[i][3] + bv[3];
    if (ACT == 1) { v0=eluf(v0); v1=eluf(v1); v2=eluf(v2); v3=eluf(v3); }
    else if (ACT == 2) { v0=sigmf_(v0); v1=sigmf_(v1); v2=sigmf_(v2); v3=sigmf_(v3); }
    if (ROWSCALE) { float s = rowscale[r]; v0*=s; v1*=s; v2*=s; v3*=s; }
    float4 o; o.x=v0; o.y=v1; o.z=v2; o.w=v3;
    *(float4*)&C[(size_t)r * ldc + n0 + tc] = o;
  }
}

// ---------------------------------------------------------------------------
// Action-encoder MLP: one block per (b,l) token. one_hot @ w1 == w1[a].
// ---------------------------------------------------------------------------
__global__ __launch_bounds__(256) void ae_kernel(
    const int* __restrict__ action,
    const float* __restrict__ w1, const float* __restrict__ b1,
    const float* __restrict__ w2, const float* __restrict__ b2,
    float* __restrict__ aenc)
{
  __shared__ float hs[256];
  const int bl = blockIdx.x;
  const int t = threadIdx.x;
  const int a = action[bl];
  hs[t] = eluf(w1[a * 256 + t] + b1[t]);
  __syncthreads();
  if (t < 32) {
    float acc = 0.f;
    for (int k = 0; k < 256; ++k) acc += hs[k] * w2[k * 32 + t];
    aenc[bl * 32 + t] = eluf(acc + b2[t]);
  }
}

// fill sa2[:, 256:288] with broadcast aenc
__global__ __launch_bounds__(256) void sa_fill_kernel(const float* __restrict__ aenc,
                                                      float* __restrict__ sa2)
{
  const int idx = blockIdx.x * 256 + threadIdx.x;  // 8192*32
  const int r = idx >> 5, c = idx & 31;
  sa2[(size_t)r * 288 + 256 + c] = aenc[(r >> 3) * 32 + c];
}

// zero sa2[:, 256:288] (total_effect accumulator; serial fallback path only)
__global__ __launch_bounds__(256) void zero_teff_kernel(float* __restrict__ sa2)
{
  const int idx = blockIdx.x * 256 + threadIdx.x;
  const int r = idx >> 5, c = idx & 31;
  sa2[(size_t)r * 288 + 256 + c] = 0.f;
}

// s_att[row] = sigmoid(dot(h_ea[row,256:512], aat_w2) + aat_b2). 4 rows/block.
__global__ __launch_bounds__(256) void satt_kernel(
    const float* __restrict__ hea, const float* __restrict__ w,
    const float* __restrict__ b, float* __restrict__ satt)
{
  const int wv = threadIdx.x >> 6;
  const int lane = threadIdx.x & 63;
  const int row = blockIdx.x * 4 + wv;
  const float* h = hea + (size_t)row * 512 + 256;
  float acc = 0.f;
#pragma unroll
  for (int m = 0; m < 4; ++m) acc += h[lane + 64 * m] * w[lane + 64 * m];
#pragma unroll
  for (int off = 32; off; off >>= 1) acc += __shfl_xor(acc, off, 64);
  if (lane == 0) satt[row] = sigmf_(acc + b[0]);
}

// ie/ia layer-2 + p_eff*p_att + accumulate into total_effect (sa2 cols 256:288).
// Serial fallback: one jj slice, RMW accumulate. 8 rows per block.
__global__ __launch_bounds__(256) void pair_l2_kernel(
    const float* __restrict__ h,
    const float* __restrict__ ie_w2, const float* __restrict__ ie_b2,
    const float* __restrict__ ia_w2, const float* __restrict__ ia_b2,
    float* __restrict__ sa2)
{
  __shared__ float hs[8][512];
  __shared__ float pas[8];
  const int r0 = blockIdx.x * 8;
  const int tid = threadIdx.x;
#pragma unroll
  for (int it = 0; it < 4; ++it) {
    const int f4 = it * 256 + tid;       // 1024 float4s
    const int rr = f4 >> 7;
    const int cc = (f4 & 127) << 2;
    *(float4*)&hs[rr][cc] = *(const float4*)&h[(size_t)(r0 + rr) * 512 + cc];
  }
  __syncthreads();
  const int row = tid >> 5;
  const int col = tid & 31;
  float pa = 0.f;
#pragma unroll
  for (int m = 0; m < 8; ++m) pa += hs[row][256 + col + 32 * m] * ia_w2[col + 32 * m];
#pragma unroll
  for (int off = 16; off; off >>= 1) pa += __shfl_xor(pa, off, 64);
  if (col == 0) pas[row] = sigmf_(pa + ia_b2[0]);
  float acc = 0.f;
  for (int k = 0; k < 256; ++k) acc += hs[row][k] * ie_w2[k * 32 + col];
  __syncthreads();
  const float val = eluf(acc + ie_b2[col]) * pas[row];
  sa2[(size_t)(r0 + row) * 288 + 256 + col] += val;
}

// Batched variant: h is [7*8192, 512]; loop jj internally, accumulate in regs,
// single write (no zero-init, no global RMW).
__global__ __launch_bounds__(256) void pair_l2_all_kernel(
    const float* __restrict__ h,
    const float* __restrict__ ie_w2, const float* __restrict__ ie_b2,
    const float* __restrict__ ia_w2, const float* __restrict__ ia_b2,
    float* __restrict__ sa2)
{
  __shared__ float hs[8][512];
  __shared__ float pas[8];
  const int r0 = blockIdx.x * 8;
  const int tid = threadIdx.x;
  const int row = tid >> 5;
  const int col = tid & 31;
  float teff = 0.f;
  for (int jj = 0; jj < 7; ++jj) {
    __syncthreads();   // previous iteration's hs fully consumed
    const float* hb = h + ((size_t)jj * BLN + r0) * 512;
#pragma unroll
    for (int it = 0; it < 4; ++it) {
      const int f4 = it * 256 + tid;
      const int rr = f4 >> 7;
      const int cc = (f4 & 127) << 2;
      *(float4*)&hs[rr][cc] = *(const float4*)&hb[(size_t)rr * 512 + cc];
    }
    __syncthreads();
    float pa = 0.f;
#pragma unroll
    for (int m = 0; m < 8; ++m) pa += hs[row][256 + col + 32 * m] * ia_w2[col + 32 * m];
#pragma unroll
    for (int off = 16; off; off >>= 1) pa += __shfl_xor(pa, off, 64);
    if (col == 0) pas[row] = sigmf_(pa + ia_b2[0]);
    float acc = 0.f;
    for (int k = 0; k < 256; ++k) acc += hs[row][k] * ie_w2[k * 32 + col];
    __syncthreads();   // pas[row] visible (and hs consumed before next jj)
    teff += eluf(acc + ie_b2[col]) * pas[row];
  }
  sa2[(size_t)(r0 + row) * 288 + 256 + col] = teff;
}

// weight concat: dst[k, 0:N]=a, dst[k, N:2N]=b  (dst is [K, 2N])
__global__ __launch_bounds__(256) void concat_w_kernel(
    const float* __restrict__ a, const float* __restrict__ b,
    float* __restrict__ dst, int N)
{
  const int idx = blockIdx.x * 256 + threadIdx.x;
  const int k = idx / (2 * N);
  const int n = idx % (2 * N);
  dst[idx] = (n < N) ? a[k * N + n] : b[k * N + (n - N)];
}

__global__ __launch_bounds__(512) void concat_b_kernel(
    const float* __restrict__ a, const float* __restrict__ b,
    float* __restrict__ dst, int N)
{
  const int t = threadIdx.x;
  dst[t] = (t < N) ? a[t] : b[t - N];
}

// ---------------------------------------------------------------------------
extern "C" void kernel_launch(void* const* d_in, const int* in_sizes, int n_in,
                              void* d_out, int out_size, void* d_ws, size_t ws_size,
                              hipStream_t stream) {
  const float* samples = (const float*)d_in[0];
  const int*   action  = (const int*)d_in[1];
  // d_in[2] mask: unused by the forward pass
  const float* in_w1  = (const float*)d_in[3];
  const float* in_b1  = (const float*)d_in[4];
  const float* in_w2  = (const float*)d_in[5];
  const float* in_b2  = (const float*)d_in[6];
  const float* ae_w1  = (const float*)d_in[7];
  const float* ae_b1  = (const float*)d_in[8];
  const float* ae_w2  = (const float*)d_in[9];
  const float* ae_b2  = (const float*)d_in[10];
  const float* eff_w1 = (const float*)d_in[11];
  const float* eff_b1 = (const float*)d_in[12];
  const float* eff_w2 = (const float*)d_in[13];
  const float* eff_b2 = (const float*)d_in[14];
  const float* aat_w1 = (const float*)d_in[15];
  const float* aat_b1 = (const float*)d_in[16];
  const float* aat_w2 = (const float*)d_in[17];
  const float* aat_b2 = (const float*)d_in[18];
  const float* pw_w1  = (const float*)d_in[19];
  const float* pw_b1  = (const float*)d_in[20];
  const float* pw_w2  = (const float*)d_in[21];
  const float* pw_b2  = (const float*)d_in[22];
  const float* ie_w1  = (const float*)d_in[23];
  const float* ie_b1  = (const float*)d_in[24];
  const float* ie_w2  = (const float*)d_in[25];
  const float* ie_b2  = (const float*)d_in[26];
  const float* ia_w1  = (const float*)d_in[27];
  const float* ia_b1  = (const float*)d_in[28];
  const float* ia_w2  = (const float*)d_in[29];
  const float* ia_b2  = (const float*)d_in[30];
  const float* fm_w1  = (const float*)d_in[31];
  const float* fm_b1  = (const float*)d_in[32];
  const float* fm_w2  = (const float*)d_in[33];
  const float* fm_b2  = (const float*)d_in[34];
  const float* out_w1 = (const float*)d_in[35];
  const float* out_b1 = (const float*)d_in[36];
  const float* out_w2 = (const float*)d_in[37];
  const float* out_b2 = (const float*)d_in[38];
  float* out = (float*)d_out;

  // workspace arena (floats)
  float* ws = (float*)d_ws;
  float* sa2     = ws;                         // [8192, 288] sa / state_enc+teff / merged_in
  float* h1      = sa2     + (size_t)BLN*288;  // [8192, 256]
  float* hea     = h1      + (size_t)BLN*256;  // [8192, 512]
  float* U       = hea     + (size_t)BLN*512;  // [8192, 512]
  float* V       = U       + (size_t)BLN*512;  // [8192, 512]
  float* pint    = V       + (size_t)BLN*512;  // [8192, 256]
  float* aenc    = pint    + (size_t)BLN*256;  // [1024, 32]
  float* satt    = aenc    + (size_t)BL*32;    // [8192]
  float* wcat_ea = satt    + BLN;              // [288, 512]
  float* bcat_ea = wcat_ea + 288*512;          // [512]
  float* wcat_ii = bcat_ea + 512;              // [256, 512]
  float* bcat_ii = wcat_ii + 256*512;          // [512]
  float* arena_end = bcat_ii + 512;            // 19,457,024 floats
  // batched pair-phase buffers (only if workspace allows)
  float* pint_all = arena_end;                      // [7*8192, 256] = 14,680,064
  float* hea_all  = pint_all + (size_t)7*BLN*256;   // [7*8192, 512] = 29,360,128
  const size_t need_batched = ((size_t)63497216) * sizeof(float);
  const bool batched = (ws_size >= need_batched);

  const dim3 blk(256);

  // weight prep
  concat_w_kernel<<<dim3(288*512/256), blk, 0, stream>>>(eff_w1, aat_w1, wcat_ea, 256);
  concat_b_kernel<<<dim3(1), dim3(512), 0, stream>>>(eff_b1, aat_b1, bcat_ea, 256);
  concat_w_kernel<<<dim3(256*512/256), blk, 0, stream>>>(ie_w1, ia_w1, wcat_ii, 256);
  concat_b_kernel<<<dim3(1), dim3(512), 0, stream>>>(ie_b1, ia_b1, bcat_ii, 256);

  // action encoder
  ae_kernel<<<dim3(BL), blk, 0, stream>>>(action, ae_w1, ae_b1, ae_w2, ae_b2, aenc);

  // in_ MLP: samples -> h1 -> sa2[:, :256]
  gemm_k<1,false,false><<<dim3(128,4), blk, 0, stream>>>(samples, 256, in_w1, 256, in_b1, h1, 256, 256, nullptr, nullptr, 0);
  gemm_k<1,false,false><<<dim3(128,4), blk, 0, stream>>>(h1, 256, in_w2, 256, in_b2, sa2, 288, 256, nullptr, nullptr, 0);
  sa_fill_kernel<<<dim3(BLN*32/256), blk, 0, stream>>>(aenc, sa2);

  // eff/aat layer1 (fused) -> hea[8192,512]
  gemm_k<1,false,false><<<dim3(128,8), blk, 0, stream>>>(sa2, 288, wcat_ea, 512, bcat_ea, hea, 512, 288, nullptr, nullptr, 0);
  // s_att
  satt_kernel<<<dim3(BLN/4), blk, 0, stream>>>(hea, aat_w2, aat_b2, satt);
  // eff layer2 with rowscale -> state_enc into sa2[:, :256]
  gemm_k<1,true,false><<<dim3(128,4), blk, 0, stream>>>(hea, 512, eff_w2, 256, eff_b2, sa2, 288, 256, satt, nullptr, 0);

  // U = senc @ pw_w1[:256,:] + pw_b1 ; V = senc @ pw_w1[256:,:]
  gemm_k<0,false,false><<<dim3(128,8), blk, 0, stream>>>(sa2, 288, pw_w1, 512, pw_b1, U, 512, 256, nullptr, nullptr, 0);
  gemm_k<0,false,false><<<dim3(128,8), blk, 0, stream>>>(sa2, 288, pw_w1 + 256*512, 512, nullptr, V, 512, 256, nullptr, nullptr, 0);

  if (batched) {
    // all 7 jj slices in one dispatch each: grid 3584 / 7168 blocks
    // (round-0 kernel is 68 VGPR / 16.9KB LDS => ~7 blocks/CU resident)
    gemm_k<1,false,true><<<dim3(128*7,4), blk, 0, stream>>>(U, 512, pw_w2, 256, pw_b2, pint_all, 256, 512, nullptr, V, -1);
    gemm_k<1,false,false><<<dim3(128*7,8), blk, 0, stream>>>(pint_all, 256, wcat_ii, 512, bcat_ii, hea_all, 512, 256, nullptr, nullptr, 0);
    pair_l2_all_kernel<<<dim3(BLN/8), blk, 0, stream>>>(hea_all, ie_w2, ie_b2, ia_w2, ia_b2, sa2);
  } else {
    // serial fallback (original path)
    zero_teff_kernel<<<dim3(BLN*32/256), blk, 0, stream>>>(sa2);
    for (int jj = 0; jj < 7; ++jj) {
      gemm_k<1,false,true><<<dim3(128,4), blk, 0, stream>>>(U, 512, pw_w2, 256, pw_b2, pint, 256, 512, nullptr, V, jj);
      gemm_k<1,false,false><<<dim3(128,8), blk, 0, stream>>>(pint, 256, wcat_ii, 512, bcat_ii, hea, 512, 256, nullptr, nullptr, 0);
      pair_l2_kernel<<<dim3(BLN/8), blk, 0, stream>>>(hea, ie_w2, ie_b2, ia_w2, ia_b2, sa2);
    }
  }

  // fm MLP: sa2[8192,288] -> h1 -> merged (pint)
  gemm_k<1,false,false><<<dim3(128,4), blk, 0, stream>>>(sa2, 288, fm_w1, 256, fm_b1, h1, 256, 288, nullptr, nullptr, 0);
  gemm_k<1,false,false><<<dim3(128,4), blk, 0, stream>>>(h1, 256, fm_w2, 256, fm_b2, pint, 256, 256, nullptr, nullptr, 0);

  // out MLP: merged -> h1 -> d_out
  gemm_k<1,false,false><<<dim3(128,4), blk, 0, stream>>>(pint, 256, out_w1, 256, out_b1, h1, 256, 256, nullptr, nullptr, 0);
  gemm_k<0,false,false><<<dim3(128,4), blk, 0, stream>>>(h1, 256, out_w2, 256, out_b2, out, 256, 256, nullptr, nullptr, 0);
}

// Round 3
// 917.344 us; speedup vs baseline: 1.5888x; 1.0447x over previous
//
#include <hip/hip_runtime.h>
#include <math.h>

// ---------------------------------------------------------------------------
// OP3 Physics Network forward, fp32. Sizes: B=32,L=32,N=8,D=256,A=16,AENC=32,EFF=32
// Tokens: BLN = 8192 node tokens, pairs = 8192*7.
// Key restructure: pairs@pw_w1 = U[i]+V[j] with U=senc@W1top+b1, V=senc@W1bot.
// Round 3: the two big batched pair GEMMs move to a 128x128 tile / 8x8
// microtile kernel (gemm128_k). Round-2 analysis: 4x4 microtile = 2.0 B
// LDS-read per FLOP -> LDS-BW-bound ~3x (47 TF @ 73% VALUBusy). 8x8 halves
// LDS traffic per FLOP and the new staging mapping is bank-conflict-free
// (all accesses <=2-way, which is free on 64-lane/32-bank).
// ---------------------------------------------------------------------------

#define BLN 8192
#define BL  1024

__device__ __forceinline__ float eluf(float x)  { return x > 0.0f ? x : expm1f(x); }
__device__ __forceinline__ float sigmf_(float x){ return 1.0f / (1.0f + expf(-x)); }

// ---------------------------------------------------------------------------
// Generic tiled GEMM: C[M,N] = act(A[M,K] @ W[K,N] + bias) [* rowscale[row]]
// 64x64 tile, BK=32, 256 threads, 4x4 per thread. Single-buffered LDS.
// Used for the M=8192 GEMMs (grid 512+ blocks) and the serial fallback.
// ---------------------------------------------------------------------------
template<int ACT, bool ROWSCALE, bool PAIRGATHER>
__global__ __launch_bounds__(256) void gemm_k(
    const float* __restrict__ A, int lda,
    const float* __restrict__ W, int ldw,
    const float* __restrict__ bias,
    float* __restrict__ C, int ldc,
    int K,
    const float* __restrict__ rowscale,
    const float* __restrict__ Vm, int jj)
{
  __shared__ float As[32][68];   // k-major, padded
  __shared__ float Ws[32][64];   // k-major (natural)
  const int m0 = blockIdx.x * 64;
  const int n0 = blockIdx.y * 64;
  const int tid = threadIdx.x;

  const int arow = tid >> 2;            // 0..63
  const int akg  = (tid & 3) << 3;      // 0,8,16,24
  const int wrow = tid >> 3;            // 0..31
  const int wcg  = (tid & 7) << 3;      // 0..56

  const int tr = (tid >> 4) << 2;       // 0..60
  const int tc = (tid & 15) << 2;       // 0..60

  const int gr = m0 + arow;
  const float* aptr;
  const float* vptr = nullptr;
  if (PAIRGATHER) {
    const int jjv = (jj >= 0) ? jj : (gr >> 13);
    const int r = gr & (BLN - 1);
    const int i = r & 7;
    const int j = jjv + ((jjv >= i) ? 1 : 0);
    const int vr = (r & ~7) | j;
    aptr = A  + (size_t)r * lda + akg;
    vptr = Vm + (size_t)vr * lda + akg;
  } else {
    aptr = A + (size_t)gr * lda + akg;
  }
  const float* wptr = W + (size_t)wrow * ldw + n0 + wcg;

  float acc[4][4] = {};

  for (int k0 = 0; k0 < K; k0 += 32) {
    float av[8];
    if (PAIRGATHER) {
      float4 u0 = *(const float4*)(aptr + k0);
      float4 u1 = *(const float4*)(aptr + k0 + 4);
      float4 v0 = *(const float4*)(vptr + k0);
      float4 v1 = *(const float4*)(vptr + k0 + 4);
      av[0]=eluf(u0.x+v0.x); av[1]=eluf(u0.y+v0.y); av[2]=eluf(u0.z+v0.z); av[3]=eluf(u0.w+v0.w);
      av[4]=eluf(u1.x+v1.x); av[5]=eluf(u1.y+v1.y); av[6]=eluf(u1.z+v1.z); av[7]=eluf(u1.w+v1.w);
    } else {
      float4 a0 = *(const float4*)(aptr + k0);
      float4 a1 = *(const float4*)(aptr + k0 + 4);
      av[0]=a0.x; av[1]=a0.y; av[2]=a0.z; av[3]=a0.w;
      av[4]=a1.x; av[5]=a1.y; av[6]=a1.z; av[7]=a1.w;
    }
    float4 w0 = *(const float4*)(wptr + (size_t)k0 * ldw);
    float4 w1 = *(const float4*)(wptr + (size_t)k0 * ldw + 4);

    __syncthreads();   // previous tile fully consumed before overwrite
#pragma unroll
    for (int i = 0; i < 8; ++i) As[akg + i][arow] = av[i];
    *(float4*)&Ws[wrow][wcg]     = w0;
    *(float4*)&Ws[wrow][wcg + 4] = w1;
    __syncthreads();

#pragma unroll
    for (int k = 0; k < 32; ++k) {
      float4 a = *(const float4*)&As[k][tr];
      float4 w = *(const float4*)&Ws[k][tc];
      acc[0][0] += a.x*w.x; acc[0][1] += a.x*w.y; acc[0][2] += a.x*w.z; acc[0][3] += a.x*w.w;
      acc[1][0] += a.y*w.x; acc[1][1] += a.y*w.y; acc[1][2] += a.y*w.z; acc[1][3] += a.y*w.w;
      acc[2][0] += a.z*w.x; acc[2][1] += a.z*w.y; acc[2][2] += a.z*w.z; acc[2][3] += a.z*w.w;
      acc[3][0] += a.w*w.x; acc[3][1] += a.w*w.y; acc[3][2] += a.w*w.z; acc[3][3] += a.w*w.w;
    }
  }

  float bv[4] = {0.f, 0.f, 0.f, 0.f};
  if (bias) {
    float4 b = *(const float4*)(bias + n0 + tc);
    bv[0]=b.x; bv[1]=b.y; bv[2]=b.z; bv[3]=b.w;
  }
#pragma unroll
  for (int i = 0; i < 4; ++i) {
    const int r = m0 + tr + i;
    float v0 = acc[i][0] + bv[0];
    float v1 = acc[i][1] + bv[1];
    float v2 = acc[i][2] + bv[2];
    float v3 = acc[i][3] + bv[3];
    if (ACT == 1) { v0=eluf(v0); v1=eluf(v1); v2=eluf(v2); v3=eluf(v3); }
    else if (ACT == 2) { v0=sigmf_(v0); v1=sigmf_(v1); v2=sigmf_(v2); v3=sigmf_(v3); }
    if (ROWSCALE) { float s = rowscale[r]; v0*=s; v1*=s; v2*=s; v3*=s; }
    float4 o; o.x=v0; o.y=v1; o.z=v2; o.w=v3;
    *(float4*)&C[(size_t)r * ldc + n0 + tc] = o;
  }
}

// ---------------------------------------------------------------------------
// Big-M GEMM: 128x128 tile, BK=32, 256 threads, 8x8 per thread.
// LDS bytes/FLOP = 1.0 (vs 2.0 for 4x4). Bank mapping (all <=2-way = free):
//  - A stage: thread (arow=tid>>1, k-half=(tid&1)*16); store As[k][arow],
//    stride 132 === 4 mod 32; k-halves 16 apart -> 4*16 === 0 mod 32, so the
//    64 lanes land 2 per bank.
//  - W stage: float4 stores, row stride 132 -> (4*wrow + 16*(wcg parity))
//    covers 16 bank-quads 2-way.
//  - A read: 4 distinct addrs/wave (broadcast 16-way). W read: 2-way.
// PAIRGATHER: A_virtual[r,k] = elu(U[r,k] + V[vrow(r),k]); jj from row>>13.
// ---------------------------------------------------------------------------
template<int ACT, bool PAIRGATHER>
__global__ __launch_bounds__(256, 3) void gemm128_k(
    const float* __restrict__ A, int lda,
    const float* __restrict__ W, int ldw,
    const float* __restrict__ bias,
    float* __restrict__ C, int ldc,
    int K,
    const float* __restrict__ Vm)
{
  __shared__ float As[32][132];
  __shared__ float Ws[32][132];
  const int m0 = blockIdx.x * 128;
  const int n0 = blockIdx.y * 128;
  const int tid = threadIdx.x;

  // staging roles
  const int arow = tid >> 1;            // 0..127
  const int ak16 = (tid & 1) << 4;      // 0,16
  const int wrow = tid >> 3;            // 0..31
  const int wcg  = (tid & 7) << 4;      // 0..112

  // compute roles: 16x16 thread grid, each owns rows {4ty+i, 64+4ty+i},
  // cols {4tx+j, 64+4tx+j}
  const int ty4 = (tid >> 4) << 2;      // 0..60
  const int tx4 = (tid & 15) << 2;      // 0..60

  const int gr = m0 + arow;
  const float* aptr;
  const float* vptr = nullptr;
  if (PAIRGATHER) {
    const int jjv = gr >> 13;
    const int r = gr & (BLN - 1);
    const int i = r & 7;
    const int j = jjv + ((jjv >= i) ? 1 : 0);
    const int vr = (r & ~7) | j;
    aptr = A  + (size_t)r * lda + ak16;
    vptr = Vm + (size_t)vr * lda + ak16;
  } else {
    aptr = A + (size_t)gr * lda + ak16;
  }
  const float* wptr = W + (size_t)wrow * ldw + n0 + wcg;

  float acc[8][8] = {};

  for (int k0 = 0; k0 < K; k0 += 32) {
    // issue global loads before the barrier (overlap with other waves)
    float4 ua[4], va[4], wa[4];
#pragma unroll
    for (int q = 0; q < 4; ++q) ua[q] = *(const float4*)(aptr + k0 + 4*q);
    if (PAIRGATHER) {
#pragma unroll
      for (int q = 0; q < 4; ++q) va[q] = *(const float4*)(vptr + k0 + 4*q);
    }
#pragma unroll
    for (int q = 0; q < 4; ++q) wa[q] = *(const float4*)(wptr + (size_t)k0 * ldw + 4*q);

    __syncthreads();   // previous tile fully consumed before overwrite
#pragma unroll
    for (int q = 0; q < 4; ++q) {
      float4 u = ua[q];
      if (PAIRGATHER) {
        float4 v = va[q];
        u.x = eluf(u.x+v.x); u.y = eluf(u.y+v.y); u.z = eluf(u.z+v.z); u.w = eluf(u.w+v.w);
      }
      As[ak16 + 4*q + 0][arow] = u.x;
      As[ak16 + 4*q + 1][arow] = u.y;
      As[ak16 + 4*q + 2][arow] = u.z;
      As[ak16 + 4*q + 3][arow] = u.w;
    }
#pragma unroll
    for (int q = 0; q < 4; ++q)
      *(float4*)&Ws[wrow][wcg + 4*q] = wa[q];
    __syncthreads();

#pragma unroll
    for (int k = 0; k < 32; ++k) {
      float4 a0 = *(const float4*)&As[k][ty4];
      float4 a1 = *(const float4*)&As[k][64 + ty4];
      float4 w0 = *(const float4*)&Ws[k][tx4];
      float4 w1 = *(const float4*)&Ws[k][64 + tx4];
      float ar[8] = {a0.x,a0.y,a0.z,a0.w,a1.x,a1.y,a1.z,a1.w};
      float wr[8] = {w0.x,w0.y,w0.z,w0.w,w1.x,w1.y,w1.z,w1.w};
#pragma unroll
      for (int i = 0; i < 8; ++i) {
#pragma unroll
        for (int j = 0; j < 8; ++j) acc[i][j] += ar[i] * wr[j];
      }
    }
  }

  float bv[8] = {0.f,0.f,0.f,0.f,0.f,0.f,0.f,0.f};
  if (bias) {
    float4 b0 = *(const float4*)(bias + n0 + tx4);
    float4 b1 = *(const float4*)(bias + n0 + 64 + tx4);
    bv[0]=b0.x; bv[1]=b0.y; bv[2]=b0.z; bv[3]=b0.w;
    bv[4]=b1.x; bv[5]=b1.y; bv[6]=b1.z; bv[7]=b1.w;
  }
#pragma unroll
  for (int ih = 0; ih < 2; ++ih) {
#pragma unroll
    for (int i = 0; i < 4; ++i) {
      const int r = m0 + ih*64 + ty4 + i;
#pragma unroll
      for (int jh = 0; jh < 2; ++jh) {
        float v0 = acc[ih*4+i][jh*4+0] + bv[jh*4+0];
        float v1 = acc[ih*4+i][jh*4+1] + bv[jh*4+1];
        float v2 = acc[ih*4+i][jh*4+2] + bv[jh*4+2];
        float v3 = acc[ih*4+i][jh*4+3] + bv[jh*4+3];
        if (ACT == 1) { v0=eluf(v0); v1=eluf(v1); v2=eluf(v2); v3=eluf(v3); }
        else if (ACT == 2) { v0=sigmf_(v0); v1=sigmf_(v1); v2=sigmf_(v2); v3=sigmf_(v3); }
        float4 o; o.x=v0; o.y=v1; o.z=v2; o.w=v3;
        *(float4*)&C[(size_t)r * ldc + n0 + jh*64 + tx4] = o;
      }
    }
  }
}

// ---------------------------------------------------------------------------
// Action-encoder MLP: one block per (b,l) token. one_hot @ w1 == w1[a].
// ---------------------------------------------------------------------------
__global__ __launch_bounds__(256) void ae_kernel(
    const int* __restrict__ action,
    const float* __restrict__ w1, const float* __restrict__ b1,
    const float* __restrict__ w2, const float* __restrict__ b2,
    float* __restrict__ aenc)
{
  __shared__ float hs[256];
  const int bl = blockIdx.x;
  const int t = threadIdx.x;
  const int a = action[bl];
  hs[t] = eluf(w1[a * 256 + t] + b1[t]);
  __syncthreads();
  if (t < 32) {
    float acc = 0.f;
    for (int k = 0; k < 256; ++k) acc += hs[k] * w2[k * 32 + t];
    aenc[bl * 32 + t] = eluf(acc + b2[t]);
  }
}

// fill sa2[:, 256:288] with broadcast aenc
__global__ __launch_bounds__(256) void sa_fill_kernel(const float* __restrict__ aenc,
                                                      float* __restrict__ sa2)
{
  const int idx = blockIdx.x * 256 + threadIdx.x;  // 8192*32
  const int r = idx >> 5, c = idx & 31;
  sa2[(size_t)r * 288 + 256 + c] = aenc[(r >> 3) * 32 + c];
}

// zero sa2[:, 256:288] (total_effect accumulator; serial fallback path only)
__global__ __launch_bounds__(256) void zero_teff_kernel(float* __restrict__ sa2)
{
  const int idx = blockIdx.x * 256 + threadIdx.x;
  const int r = idx >> 5, c = idx & 31;
  sa2[(size_t)r * 288 + 256 + c] = 0.f;
}

// s_att[row] = sigmoid(dot(h_ea[row,256:512], aat_w2) + aat_b2). 4 rows/block.
__global__ __launch_bounds__(256) void satt_kernel(
    const float* __restrict__ hea, const float* __restrict__ w,
    const float* __restrict__ b, float* __restrict__ satt)
{
  const int wv = threadIdx.x >> 6;
  const int lane = threadIdx.x & 63;
  const int row = blockIdx.x * 4 + wv;
  const float* h = hea + (size_t)row * 512 + 256;
  float acc = 0.f;
#pragma unroll
  for (int m = 0; m < 4; ++m) acc += h[lane + 64 * m] * w[lane + 64 * m];
#pragma unroll
  for (int off = 32; off; off >>= 1) acc += __shfl_xor(acc, off, 64);
  if (lane == 0) satt[row] = sigmf_(acc + b[0]);
}

// ie/ia layer-2 + p_eff*p_att + accumulate into total_effect (sa2 cols 256:288).
// Serial fallback: one jj slice, RMW accumulate. 8 rows per block.
__global__ __launch_bounds__(256) void pair_l2_kernel(
    const float* __restrict__ h,
    const float* __restrict__ ie_w2, const float* __restrict__ ie_b2,
    const float* __restrict__ ia_w2, const float* __restrict__ ia_b2,
    float* __restrict__ sa2)
{
  __shared__ float hs[8][512];
  __shared__ float pas[8];
  const int r0 = blockIdx.x * 8;
  const int tid = threadIdx.x;
#pragma unroll
  for (int it = 0; it < 4; ++it) {
    const int f4 = it * 256 + tid;       // 1024 float4s
    const int rr = f4 >> 7;
    const int cc = (f4 & 127) << 2;
    *(float4*)&hs[rr][cc] = *(const float4*)&h[(size_t)(r0 + rr) * 512 + cc];
  }
  __syncthreads();
  const int row = tid >> 5;
  const int col = tid & 31;
  float pa = 0.f;
#pragma unroll
  for (int m = 0; m < 8; ++m) pa += hs[row][256 + col + 32 * m] * ia_w2[col + 32 * m];
#pragma unroll
  for (int off = 16; off; off >>= 1) pa += __shfl_xor(pa, off, 64);
  if (col == 0) pas[row] = sigmf_(pa + ia_b2[0]);
  float acc = 0.f;
  for (int k = 0; k < 256; ++k) acc += hs[row][k] * ie_w2[k * 32 + col];
  __syncthreads();
  const float val = eluf(acc + ie_b2[col]) * pas[row];
  sa2[(size_t)(r0 + row) * 288 + 256 + col] += val;
}

// Batched variant: h is [7*8192, 512]; loop jj internally, accumulate in regs,
// single write (no zero-init, no global RMW).
__global__ __launch_bounds__(256) void pair_l2_all_kernel(
    const float* __restrict__ h,
    const float* __restrict__ ie_w2, const float* __restrict__ ie_b2,
    const float* __restrict__ ia_w2, const float* __restrict__ ia_b2,
    float* __restrict__ sa2)
{
  __shared__ float hs[8][512];
  __shared__ float pas[8];
  const int r0 = blockIdx.x * 8;
  const int tid = threadIdx.x;
  const int row = tid >> 5;
  const int col = tid & 31;
  float teff = 0.f;
  for (int jj = 0; jj < 7; ++jj) {
    __syncthreads();   // previous iteration's hs fully consumed
    const float* hb = h + ((size_t)jj * BLN + r0) * 512;
#pragma unroll
    for (int it = 0; it < 4; ++it) {
      const int f4 = it * 256 + tid;
      const int rr = f4 >> 7;
      const int cc = (f4 & 127) << 2;
      *(float4*)&hs[rr][cc] = *(const float4*)&hb[(size_t)rr * 512 + cc];
    }
    __syncthreads();
    float pa = 0.f;
#pragma unroll
    for (int m = 0; m < 8; ++m) pa += hs[row][256 + col + 32 * m] * ia_w2[col + 32 * m];
#pragma unroll
    for (int off = 16; off; off >>= 1) pa += __shfl_xor(pa, off, 64);
    if (col == 0) pas[row] = sigmf_(pa + ia_b2[0]);
    float acc = 0.f;
    for (int k = 0; k < 256; ++k) acc += hs[row][k] * ie_w2[k * 32 + col];
    __syncthreads();   // pas[row] visible (and hs consumed before next jj)
    teff += eluf(acc + ie_b2[col]) * pas[row];
  }
  sa2[(size_t)(r0 + row) * 288 + 256 + col] = teff;
}

// weight concat: dst[k, 0:N]=a, dst[k, N:2N]=b  (dst is [K, 2N])
__global__ __launch_bounds__(256) void concat_w_kernel(
    const float* __restrict__ a, const float* __restrict__ b,
    float* __restrict__ dst, int N)
{
  const int idx = blockIdx.x * 256 + threadIdx.x;
  const int k = idx / (2 * N);
  const int n = idx % (2 * N);
  dst[idx] = (n < N) ? a[k * N + n] : b[k * N + (n - N)];
}

__global__ __launch_bounds__(512) void concat_b_kernel(
    const float* __restrict__ a, const float* __restrict__ b,
    float* __restrict__ dst, int N)
{
  const int t = threadIdx.x;
  dst[t] = (t < N) ? a[t] : b[t - N];
}

// ---------------------------------------------------------------------------
extern "C" void kernel_launch(void* const* d_in, const int* in_sizes, int n_in,
                              void* d_out, int out_size, void* d_ws, size_t ws_size,
                              hipStream_t stream) {
  const float* samples = (const float*)d_in[0];
  const int*   action  = (const int*)d_in[1];
  // d_in[2] mask: unused by the forward pass
  const float* in_w1  = (const float*)d_in[3];
  const float* in_b1  = (const float*)d_in[4];
  const float* in_w2  = (const float*)d_in[5];
  const float* in_b2  = (const float*)d_in[6];
  const float* ae_w1  = (const float*)d_in[7];
  const float* ae_b1  = (const float*)d_in[8];
  const float* ae_w2  = (const float*)d_in[9];
  const float* ae_b2  = (const float*)d_in[10];
  const float* eff_w1 = (const float*)d_in[11];
  const float* eff_b1 = (const float*)d_in[12];
  const float* eff_w2 = (const float*)d_in[13];
  const float* eff_b2 = (const float*)d_in[14];
  const float* aat_w1 = (const float*)d_in[15];
  const float* aat_b1 = (const float*)d_in[16];
  const float* aat_w2 = (const float*)d_in[17];
  const float* aat_b2 = (const float*)d_in[18];
  const float* pw_w1  = (const float*)d_in[19];
  const float* pw_b1  = (const float*)d_in[20];
  const float* pw_w2  = (const float*)d_in[21];
  const float* pw_b2  = (const float*)d_in[22];
  const float* ie_w1  = (const float*)d_in[23];
  const float* ie_b1  = (const float*)d_in[24];
  const float* ie_w2  = (const float*)d_in[25];
  const float* ie_b2  = (const float*)d_in[26];
  const float* ia_w1  = (const float*)d_in[27];
  const float* ia_b1  = (const float*)d_in[28];
  const float* ia_w2  = (const float*)d_in[29];
  const float* ia_b2  = (const float*)d_in[30];
  const float* fm_w1  = (const float*)d_in[31];
  const float* fm_b1  = (const float*)d_in[32];
  const float* fm_w2  = (const float*)d_in[33];
  const float* fm_b2  = (const float*)d_in[34];
  const float* out_w1 = (const float*)d_in[35];
  const float* out_b1 = (const float*)d_in[36];
  const float* out_w2 = (const float*)d_in[37];
  const float* out_b2 = (const float*)d_in[38];
  float* out = (float*)d_out;

  // workspace arena (floats)
  float* ws = (float*)d_ws;
  float* sa2     = ws;                         // [8192, 288] sa / state_enc+teff / merged_in
  float* h1      = sa2     + (size_t)BLN*288;  // [8192, 256]
  float* hea     = h1      + (size_t)BLN*256;  // [8192, 512]
  float* U       = hea     + (size_t)BLN*512;  // [8192, 512]
  float* V       = U       + (size_t)BLN*512;  // [8192, 512]
  float* pint    = V       + (size_t)BLN*512;  // [8192, 256]
  float* aenc    = pint    + (size_t)BLN*256;  // [1024, 32]
  float* satt    = aenc    + (size_t)BL*32;    // [8192]
  float* wcat_ea = satt    + BLN;              // [288, 512]
  float* bcat_ea = wcat_ea + 288*512;          // [512]
  float* wcat_ii = bcat_ea + 512;              // [256, 512]
  float* bcat_ii = wcat_ii + 256*512;          // [512]
  float* arena_end = bcat_ii + 512;            // 19,457,024 floats
  // batched pair-phase buffers (only if workspace allows)
  float* pint_all = arena_end;                      // [7*8192, 256] = 14,680,064
  float* hea_all  = pint_all + (size_t)7*BLN*256;   // [7*8192, 512] = 29,360,128
  const size_t need_batched = ((size_t)63497216) * sizeof(float);
  const bool batched = (ws_size >= need_batched);

  const dim3 blk(256);

  // weight prep
  concat_w_kernel<<<dim3(288*512/256), blk, 0, stream>>>(eff_w1, aat_w1, wcat_ea, 256);
  concat_b_kernel<<<dim3(1), dim3(512), 0, stream>>>(eff_b1, aat_b1, bcat_ea, 256);
  concat_w_kernel<<<dim3(256*512/256), blk, 0, stream>>>(ie_w1, ia_w1, wcat_ii, 256);
  concat_b_kernel<<<dim3(1), dim3(512), 0, stream>>>(ie_b1, ia_b1, bcat_ii, 256);

  // action encoder
  ae_kernel<<<dim3(BL), blk, 0, stream>>>(action, ae_w1, ae_b1, ae_w2, ae_b2, aenc);

  // in_ MLP: samples -> h1 -> sa2[:, :256]
  gemm_k<1,false,false><<<dim3(128,4), blk, 0, stream>>>(samples, 256, in_w1, 256, in_b1, h1, 256, 256, nullptr, nullptr, 0);
  gemm_k<1,false,false><<<dim3(128,4), blk, 0, stream>>>(h1, 256, in_w2, 256, in_b2, sa2, 288, 256, nullptr, nullptr, 0);
  sa_fill_kernel<<<dim3(BLN*32/256), blk, 0, stream>>>(aenc, sa2);

  // eff/aat layer1 (fused) -> hea[8192,512]
  gemm_k<1,false,false><<<dim3(128,8), blk, 0, stream>>>(sa2, 288, wcat_ea, 512, bcat_ea, hea, 512, 288, nullptr, nullptr, 0);
  // s_att
  satt_kernel<<<dim3(BLN/4), blk, 0, stream>>>(hea, aat_w2, aat_b2, satt);
  // eff layer2 with rowscale -> state_enc into sa2[:, :256]
  gemm_k<1,true,false><<<dim3(128,4), blk, 0, stream>>>(hea, 512, eff_w2, 256, eff_b2, sa2, 288, 256, satt, nullptr, 0);

  // U = senc @ pw_w1[:256,:] + pw_b1 ; V = senc @ pw_w1[256:,:]
  gemm_k<0,false,false><<<dim3(128,8), blk, 0, stream>>>(sa2, 288, pw_w1, 512, pw_b1, U, 512, 256, nullptr, nullptr, 0);
  gemm_k<0,false,false><<<dim3(128,8), blk, 0, stream>>>(sa2, 288, pw_w1 + 256*512, 512, nullptr, V, 512, 256, nullptr, nullptr, 0);

  if (batched) {
    // all 7 jj slices, 128x128-tile 8x8-microtile kernel:
    // pint: M=57344, N=256, K=512 -> grid 448x2; ie/ia: N=512, K=256 -> 448x4
    gemm128_k<1,true ><<<dim3(448,2), blk, 0, stream>>>(U, 512, pw_w2, 256, pw_b2, pint_all, 256, 512, V);
    gemm128_k<1,false><<<dim3(448,4), blk, 0, stream>>>(pint_all, 256, wcat_ii, 512, bcat_ii, hea_all, 512, 256, nullptr);
    pair_l2_all_kernel<<<dim3(BLN/8), blk, 0, stream>>>(hea_all, ie_w2, ie_b2, ia_w2, ia_b2, sa2);
  } else {
    // serial fallback (original path)
    zero_teff_kernel<<<dim3(BLN*32/256), blk, 0, stream>>>(sa2);
    for (int jj = 0; jj < 7; ++jj) {
      gemm_k<1,false,true><<<dim3(128,4), blk, 0, stream>>>(U, 512, pw_w2, 256, pw_b2, pint, 256, 512, nullptr, V, jj);
      gemm_k<1,false,false><<<dim3(128,8), blk, 0, stream>>>(pint, 256, wcat_ii, 512, bcat_ii, hea, 512, 256, nullptr, nullptr, 0);
      pair_l2_kernel<<<dim3(BLN/8), blk, 0, stream>>>(hea, ie_w2, ie_b2, ia_w2, ia_b2, sa2);
    }
  }

  // fm MLP: sa2[8192,288] -> h1 -> merged (pint)
  gemm_k<1,false,false><<<dim3(128,4), blk, 0, stream>>>(sa2, 288, fm_w1, 256, fm_b1, h1, 256, 288, nullptr, nullptr, 0);
  gemm_k<1,false,false><<<dim3(128,4), blk, 0, stream>>>(h1, 256, fm_w2, 256, fm_b2, pint, 256, 256, nullptr, nullptr, 0);

  // out MLP: merged -> h1 -> d_out
  gemm_k<1,false,false><<<dim3(128,4), blk, 0, stream>>>(pint, 256, out_w1, 256, out_b1, h1, 256, 256, nullptr, nullptr, 0);
  gemm_k<0,false,false><<<dim3(128,4), blk, 0, stream>>>(h1, 256, out_w2, 256, out_b2, out, 256, 256, nullptr, nullptr, 0);
}